// Round 1
// baseline (263.015 us; speedup 1.0000x reference)
//
#include <hip/hip_runtime.h>
#include <hip/hip_bf16.h>
#include <cstdint>

#define N_ROWS 8192
#define DIM    1024

typedef __attribute__((ext_vector_type(4))) float  f32x4;
typedef __attribute__((ext_vector_type(8))) __bf16 bf16x8;

__device__ __forceinline__ unsigned short f2bf(float x) {
    unsigned int u = __float_as_uint(x);
    u += 0x7fffu + ((u >> 16) & 1u);   // round-to-nearest-even
    return (unsigned short)(u >> 16);
}

// ---------------------------------------------------------------------------
// Kernel 1: per-row L2 normalize (fp32 -> bf16), fp32 diagonal logit, zero S.
// One block per row, 256 threads, 4 f32 per thread.
// ---------------------------------------------------------------------------
__global__ __launch_bounds__(256) void normalize_kernel(
    const float* __restrict__ A, const float* __restrict__ B,
    short* __restrict__ Abf, short* __restrict__ Bbf,
    float* __restrict__ diag, float* __restrict__ S)
{
    const int row  = blockIdx.x;
    const int t    = threadIdx.x;
    const int lane = t & 63;
    const int wave = t >> 6;

    const float4 a = reinterpret_cast<const float4*>(A)[row * (DIM / 4) + t];
    const float4 b = reinterpret_cast<const float4*>(B)[row * (DIM / 4) + t];

    float ssA = a.x * a.x + a.y * a.y + a.z * a.z + a.w * a.w;
    float ssB = b.x * b.x + b.y * b.y + b.z * b.z + b.w * b.w;
#pragma unroll
    for (int m = 1; m < 64; m <<= 1) {
        ssA += __shfl_xor(ssA, m);
        ssB += __shfl_xor(ssB, m);
    }
    __shared__ float redA[4], redB[4];
    if (lane == 0) { redA[wave] = ssA; redB[wave] = ssB; }
    __syncthreads();
    ssA = redA[0] + redA[1] + redA[2] + redA[3];
    ssB = redB[0] + redB[1] + redB[2] + redB[3];

    const float ia = 1.0f / fmaxf(sqrtf(ssA), 1e-8f);
    const float ib = 1.0f / fmaxf(sqrtf(ssB), 1e-8f);

    const float anx = a.x * ia, any = a.y * ia, anz = a.z * ia, anw = a.w * ia;
    const float bnx = b.x * ib, bny = b.y * ib, bnz = b.z * ib, bnw = b.w * ib;

    ushort4 pa, pb;
    pa.x = f2bf(anx); pa.y = f2bf(any); pa.z = f2bf(anz); pa.w = f2bf(anw);
    pb.x = f2bf(bnx); pb.y = f2bf(bny); pb.z = f2bf(bnz); pb.w = f2bf(bnw);
    reinterpret_cast<ushort4*>(Abf)[row * (DIM / 4) + t] = pa;
    reinterpret_cast<ushort4*>(Bbf)[row * (DIM / 4) + t] = pb;

    // fp32 diagonal logit (more accurate than the bf16 GEMM would give)
    float d = anx * bnx + any * bny + anz * bnz + anw * bnw;
#pragma unroll
    for (int m = 1; m < 64; m <<= 1) d += __shfl_xor(d, m);
    __shared__ float redD[4];
    if (lane == 0) redD[wave] = d;
    __syncthreads();
    if (t == 0) {
        diag[row] = (redD[0] + redD[1] + redD[2] + redD[3]) * 10.0f;  // /T
        S[row] = 0.0f;   // ws is poisoned 0xAA each launch
    }
}

// ---------------------------------------------------------------------------
// Kernel 2: fused bf16 GEMM (A·B^T) + exp(logit-10) + per-row partial sums.
// m97 structure: 128x128 tile, BK=32, 4 waves, 16x16x32 MFMA,
// global_load_lds width 16, linear LDS, 2 barriers / K-step.
// ---------------------------------------------------------------------------
#define BM 128
#define BN 128
#define BK 32
#define KSTEPS (DIM / BK)

__global__ __launch_bounds__(256) void gemm_lse_kernel(
    const short* __restrict__ Abf, const short* __restrict__ Bbf,
    float* __restrict__ S)
{
    __shared__ short As[BM * BK];   // 8 KiB
    __shared__ short Bs[BN * BK];   // 8 KiB

    const int t    = threadIdx.x;
    const int lane = t & 63;
    const int wave = t >> 6;
    const int wr   = wave >> 1;      // wave row quadrant (0..1)
    const int wc   = wave & 1;       // wave col quadrant (0..1)
    const int lm   = lane & 15;
    const int lk   = lane >> 4;

    const int tileM = blockIdx.x >> 6;    // 64 row tiles
    const int tileN = blockIdx.x & 63;    // 64 col tiles (consecutive bids share A panel)

    const short* Ab = Abf + (size_t)tileM * BM * DIM;
    const short* Bb = Bbf + (size_t)tileN * BN * DIM;

    f32x4 acc[4][4];
#pragma unroll
    for (int m = 0; m < 4; m++)
#pragma unroll
        for (int n = 0; n < 4; n++) acc[m][n] = (f32x4){0.f, 0.f, 0.f, 0.f};

    for (int kk = 0; kk < KSTEPS; ++kk) {
        const int k0 = kk * BK;
        // stage 128x32 bf16 tiles of A and B: 2x 16B loads per thread each
#pragma unroll
        for (int i = 0; i < 2; i++) {
            const int s   = i * 256 + t;
            const int row = s >> 2;
            const int cs  = s & 3;
            __builtin_amdgcn_global_load_lds(
                (const __attribute__((address_space(1))) void*)(Ab + (size_t)row * DIM + k0 + cs * 8),
                (__attribute__((address_space(3))) void*)(As + s * 8), 16, 0, 0);
            __builtin_amdgcn_global_load_lds(
                (const __attribute__((address_space(1))) void*)(Bb + (size_t)row * DIM + k0 + cs * 8),
                (__attribute__((address_space(3))) void*)(Bs + s * 8), 16, 0, 0);
        }
        __syncthreads();   // drains vmcnt before use

        bf16x8 af[4], bfr[4];
#pragma unroll
        for (int m = 0; m < 4; m++)
            af[m] = *reinterpret_cast<const bf16x8*>(&As[(wr * 64 + m * 16 + lm) * BK + lk * 8]);
#pragma unroll
        for (int n = 0; n < 4; n++)
            bfr[n] = *reinterpret_cast<const bf16x8*>(&Bs[(wc * 64 + n * 16 + lm) * BK + lk * 8]);

#pragma unroll
        for (int m = 0; m < 4; m++)
#pragma unroll
            for (int n = 0; n < 4; n++)
                acc[m][n] = __builtin_amdgcn_mfma_f32_16x16x32_bf16(af[m], bfr[n], acc[m][n], 0, 0, 0);
        __syncthreads();   // protect LDS before next stage
    }

    // Epilogue: x = acc*10; e = exp2((x-10)*log2e); per-row sum over 128 cols.
    // C/D layout: col = lane&15, row = (lane>>4)*4 + reg  [m89/m91]
    float* rowpart = (float*)As;     // reuse LDS (post-barrier): [128][2] floats
    constexpr float C1 = 14.4269504088896340736f;   // 10 * log2(e)

    float rs[4][4];
#pragma unroll
    for (int m = 0; m < 4; m++) {
#pragma unroll
        for (int r = 0; r < 4; r++) {
            float ssum = 0.f;
#pragma unroll
            for (int n = 0; n < 4; n++)
                ssum += exp2f(fmaf(acc[m][n][r], C1, -C1));
            // reduce across the 16 lanes holding this row's 16 cols
#pragma unroll
            for (int msk = 1; msk < 16; msk <<= 1) ssum += __shfl_xor(ssum, msk);
            rs[m][r] = ssum;
        }
    }
    if (lm == 0) {
#pragma unroll
        for (int m = 0; m < 4; m++)
#pragma unroll
            for (int r = 0; r < 4; r++)
                rowpart[(wr * 64 + m * 16 + lk * 4 + r) * 2 + wc] = rs[m][r];
    }
    __syncthreads();
    if (t < BM) {
        const float v = rowpart[t * 2 + 0] + rowpart[t * 2 + 1];
        atomicAdd(&S[tileM * BM + t], v);   // device-scope by default
    }
}

// ---------------------------------------------------------------------------
// Kernel 3: loss = mean_i( 10 + log(S_i) - diag_i )
// ---------------------------------------------------------------------------
__global__ __launch_bounds__(1024) void loss_kernel(
    const float* __restrict__ S, const float* __restrict__ diag,
    float* __restrict__ out)
{
    const int t = threadIdx.x;
    float acc = 0.f;
    for (int i = t; i < N_ROWS; i += 1024)
        acc += 10.0f + logf(S[i]) - diag[i];
#pragma unroll
    for (int m = 1; m < 64; m <<= 1) acc += __shfl_xor(acc, m);
    __shared__ float red[16];
    if ((t & 63) == 0) red[t >> 6] = acc;
    __syncthreads();
    if (t == 0) {
        float s = 0.f;
        for (int i = 0; i < 16; i++) s += red[i];
        out[0] = s * (1.0f / N_ROWS);
    }
}

// ---------------------------------------------------------------------------
extern "C" void kernel_launch(void* const* d_in, const int* in_sizes, int n_in,
                              void* d_out, int out_size, void* d_ws, size_t ws_size,
                              hipStream_t stream)
{
    const float* A = (const float*)d_in[0];   // image_emb  [8192,1024] f32
    const float* B = (const float*)d_in[1];   // sensor_emb [8192,1024] f32
    float* out = (float*)d_out;

    // workspace carve: bf16 A (16MB) | bf16 B (16MB) | S (32KB) | diag (32KB)
    short* a_bf = (short*)d_ws;
    short* b_bf = a_bf + (size_t)N_ROWS * DIM;
    float* S    = (float*)(b_bf + (size_t)N_ROWS * DIM);
    float* diag = S + N_ROWS;

    normalize_kernel<<<N_ROWS, 256, 0, stream>>>(A, B, a_bf, b_bf, diag, S);
    gemm_lse_kernel<<<(N_ROWS / BM) * (N_ROWS / BN), 256, 0, stream>>>(a_bf, b_bf, S);
    loss_kernel<<<1, 1024, 0, stream>>>(S, diag, out);
}